// Round 7
// baseline (326.073 us; speedup 1.0000x reference)
//
#include <hip/hip_runtime.h>

// IF spiking neuron, T=8 over (B=32, T=8, CHW=200704) fp32. Streaming:
// 205 MB in + 205 MB out. Cache-policy 2x2 exploration, final quadrant:
// NT loads (best so far, R4/R6) + TEMPORAL stores (let MALL absorb the
// write stream and batch writebacks; full-line wave writes skip RFO).
// VPT=1, interleaved loop (VPT/burst shown neutral in R4/R6).

typedef float v4f __attribute__((ext_vector_type(4)));

#define CHW_VEC 50176   // 64*56*56 / 4
#define TSTEPS 8
#define NBATCH 32
#define BLK 256

__global__ __launch_bounds__(BLK) void IF_33122787787165_kernel(
    const v4f* __restrict__ x, v4f* __restrict__ out) {
    const unsigned i = blockIdx.x * BLK + threadIdx.x;   // vec4 idx in CHW
    const unsigned b = blockIdx.y;
    const unsigned base = b * (TSTEPS * CHW_VEC) + i;

    v4f mem = (v4f)(0.0f);
#pragma unroll
    for (int t = 0; t < TSTEPS; ++t) {
        const v4f xt = __builtin_nontemporal_load(&x[base + (unsigned)t * CHW_VEC]);
        v4f m = mem + xt;
        v4f s;
        s.x = (m.x > 1.0f) ? 1.0f : 0.0f;
        s.y = (m.y > 1.0f) ? 1.0f : 0.0f;
        s.z = (m.z > 1.0f) ? 1.0f : 0.0f;
        s.w = (m.w > 1.0f) ? 1.0f : 0.0f;
        m.x = (m.x > 1.0f) ? 0.0f : m.x;
        m.y = (m.y > 1.0f) ? 0.0f : m.y;
        m.z = (m.z > 1.0f) ? 0.0f : m.z;
        m.w = (m.w > 1.0f) ? 0.0f : m.w;
        mem = m;
        out[base + (unsigned)t * CHW_VEC] = s;   // temporal store
    }
}

extern "C" void kernel_launch(void* const* d_in, const int* in_sizes, int n_in,
                              void* d_out, int out_size, void* d_ws, size_t ws_size,
                              hipStream_t stream) {
    const v4f* x = (const v4f*)d_in[0];
    v4f* out = (v4f*)d_out;
    dim3 grid(CHW_VEC / BLK, NBATCH);  // 196 x 32 blocks
    IF_33122787787165_kernel<<<grid, BLK, 0, stream>>>(x, out);
}

// Round 8
// 319.610 us; speedup vs baseline: 1.0202x; 1.0202x over previous
//
#include <hip/hip_runtime.h>

// IF spiking neuron, T=8 over (B=32, T=8, CHW=200704) fp32. Streaming,
// zero-reuse: 205 MB in + 205 MB out. FINAL: nontemporal BOTH directions —
// measured-best quadrant of the cache-policy 2x2:
//   temporal/temporal 330.4 | temporal/nt 343.9
//   nt/temporal       326.1 | nt/nt       320.2  <-- this kernel
// VPT=1, interleaved loop (VPT=2 / burst-load variants measured neutral).
// 6272 blocks (24.5/CU), fully coalesced dwordx4, occupancy-unconstrained.

typedef float v4f __attribute__((ext_vector_type(4)));

#define CHW_VEC 50176   // 64*56*56 / 4
#define TSTEPS 8
#define NBATCH 32
#define BLK 256

__global__ __launch_bounds__(BLK) void IF_33122787787165_kernel(
    const v4f* __restrict__ x, v4f* __restrict__ out) {
    const unsigned i = blockIdx.x * BLK + threadIdx.x;   // vec4 idx in CHW
    const unsigned b = blockIdx.y;
    const unsigned base = b * (TSTEPS * CHW_VEC) + i;

    v4f mem = (v4f)(0.0f);
#pragma unroll
    for (int t = 0; t < TSTEPS; ++t) {
        const v4f xt = __builtin_nontemporal_load(&x[base + (unsigned)t * CHW_VEC]);
        v4f m = mem + xt;
        v4f s;
        s.x = (m.x > 1.0f) ? 1.0f : 0.0f;
        s.y = (m.y > 1.0f) ? 1.0f : 0.0f;
        s.z = (m.z > 1.0f) ? 1.0f : 0.0f;
        s.w = (m.w > 1.0f) ? 1.0f : 0.0f;
        m.x = (m.x > 1.0f) ? 0.0f : m.x;
        m.y = (m.y > 1.0f) ? 0.0f : m.y;
        m.z = (m.z > 1.0f) ? 0.0f : m.z;
        m.w = (m.w > 1.0f) ? 0.0f : m.w;
        mem = m;
        __builtin_nontemporal_store(s, &out[base + (unsigned)t * CHW_VEC]);
    }
}

extern "C" void kernel_launch(void* const* d_in, const int* in_sizes, int n_in,
                              void* d_out, int out_size, void* d_ws, size_t ws_size,
                              hipStream_t stream) {
    const v4f* x = (const v4f*)d_in[0];
    v4f* out = (v4f*)d_out;
    dim3 grid(CHW_VEC / BLK, NBATCH);  // 196 x 32 blocks
    IF_33122787787165_kernel<<<grid, BLK, 0, stream>>>(x, out);
}